// Round 4
// baseline (204.683 us; speedup 1.0000x reference)
//
#include <hip/hip_runtime.h>

typedef short bf16x8 __attribute__((ext_vector_type(8)));
typedef float f32x4 __attribute__((ext_vector_type(4)));

__device__ __forceinline__ unsigned short f2b(float f) {
    unsigned int u = __builtin_bit_cast(unsigned int, f);
    unsigned int r = u + 0x7FFFu + ((u >> 16) & 1u);
    return (unsigned short)(r >> 16);
}
__device__ __forceinline__ float b2f(unsigned short v) {
    return __builtin_bit_cast(float, (unsigned int)v << 16);
}

// ---------------------------------------------------------------------------
// K0: convert gate_road_w[:, :256] to bf16 (only weight still consumed raw).
__global__ __launch_bounds__(256) void k_prep(const float* __restrict__ w3,
                                              unsigned short* __restrict__ W3b) {
    int i = blockIdx.x * 256 + threadIdx.x;   // 65536
    int o = i >> 8, k = i & 255;
    W3b[i] = f2b(w3[o * 512 + k]);
}

// ---------------------------------------------------------------------------
// K_wc: fold road_proj into road_qkv(k,v):  Wc[o] = wqkv_sel[o] @ W1  (fp32),
// bc[o] = wqkv_sel[o]@b1 + bqkv_sel.  o<256: k-row (3c+1); o>=256: v-row (3c+2).
// grid 64 blocks x 8 rows, 256 threads.
__global__ __launch_bounds__(256) void k_wc(const float* __restrict__ w1,
                                            const float* __restrict__ wqkv,
                                            const float* __restrict__ b1,
                                            const float* __restrict__ bqkv,
                                            unsigned short* __restrict__ Wcb,
                                            float* __restrict__ bcv) {
    int t = threadIdx.x;
    int o0 = blockIdx.x * 8;
    __shared__ float sel[8][256];
    __shared__ float red[8][4];
    #pragma unroll
    for (int r = 0; r < 8; r++) {
        int o = o0 + r;
        int c = (o < 256) ? o : o - 256;
        int g = (o < 256) ? 1 : 2;
        sel[r][t] = wqkv[(size_t)(3 * c + g) * 256 + t];
    }
    __syncthreads();
    float b1v = b1[t];
    #pragma unroll
    for (int r = 0; r < 8; r++) {
        float v = sel[r][t] * b1v;
        for (int m = 32; m; m >>= 1) v += __shfl_xor(v, m, 64);
        if ((t & 63) == 0) red[r][t >> 6] = v;
    }
    __syncthreads();
    if (t < 8) {
        int o = o0 + t;
        int c = (o < 256) ? o : o - 256;
        int g = (o < 256) ? 1 : 2;
        bcv[o] = red[t][0] + red[t][1] + red[t][2] + red[t][3] + bqkv[3 * c + g];
    }
    float acc[8] = {};
    #pragma unroll 4
    for (int m = 0; m < 256; m++) {
        float w1v = w1[(size_t)m * 256 + t];
        #pragma unroll
        for (int r = 0; r < 8; r++) acc[r] += sel[r][m] * w1v;
    }
    #pragma unroll
    for (int r = 0; r < 8; r++) Wcb[(size_t)(o0 + r) * 256 + t] = f2b(acc[r]);
}

// ---------------------------------------------------------------------------
// K1: tiny vector chains: ext_p -> eqkv -> (ext_q, ext_v) -> road_vec -> rg_const
__global__ __launch_bounds__(256) void k_tiny(const float* __restrict__ ext_context,
                                              const float* __restrict__ ext_proj_w,
                                              const float* __restrict__ ext_proj_b,
                                              const float* __restrict__ ext_qkv_w,
                                              const float* __restrict__ ext_qkv_b,
                                              const float* __restrict__ road_out_w,
                                              const float* __restrict__ road_out_b,
                                              const float* __restrict__ gate_road_w,
                                              const float* __restrict__ gate_road_b,
                                              float* __restrict__ ext_q,
                                              float* __restrict__ road_vec,
                                              float* __restrict__ rg_const) {
    int b = blockIdx.x, c = threadIdx.x;
    __shared__ float ctx[64], extp[256], extv[256], rv[256];
    if (c < 64) ctx[c] = ext_context[b * 64 + c];
    __syncthreads();
    float s = ext_proj_b[c];
    #pragma unroll 4
    for (int k = 0; k < 64; k++) s += ext_proj_w[c * 64 + k] * ctx[k];
    extp[c] = s;
    __syncthreads();
    float q = ext_qkv_b[c], v = ext_qkv_b[512 + c];
    #pragma unroll 4
    for (int k = 0; k < 256; k++) {
        float p = extp[k];
        q += ext_qkv_w[c * 256 + k] * p;
        v += ext_qkv_w[(512 + c) * 256 + k] * p;
    }
    ext_q[b * 256 + c] = q;
    extv[c] = v;
    __syncthreads();
    float r = road_out_b[c];
    #pragma unroll 4
    for (int k = 0; k < 256; k++) r += road_out_w[c * 256 + k] * extv[k];
    road_vec[b * 256 + c] = r;
    rv[c] = r;
    __syncthreads();
    float g = gate_road_b[c];
    #pragma unroll 4
    for (int k = 0; k < 256; k++) g += gate_road_w[c * 512 + 256 + k] * rv[k];
    rg_const[b * 256 + c] = g;
}

// ---------------------------------------------------------------------------
// K_mean
__global__ __launch_bounds__(256) void k_mean(const float* __restrict__ low,
                                              float* __restrict__ mean_low) {
    int bc = blockIdx.x, t = threadIdx.x;
    const f32x4* p4 = (const f32x4*)(low + (size_t)bc * 4096);
    float s = 0.f;
    for (int i = t; i < 1024; i += 256) {
        f32x4 v = p4[i];
        s += v[0] + v[1] + v[2] + v[3];
    }
    for (int m = 32; m; m >>= 1) s += __shfl_xor(s, m, 64);
    __shared__ float red[4];
    if ((t & 63) == 0) red[t >> 6] = s;
    __syncthreads();
    if (t == 0) mean_low[bc] = (red[0] + red[1] + red[2] + red[3]) * (1.0f / 4096.0f);
}

// ---------------------------------------------------------------------------
// K2: single fused GEMM: X(64px x 256) * Wc^T(512) -> [K: scores | V: bf16]
// block 512 (8 waves: 2 wm x 4 wn), grid 512 (8 b x 64 tiles). LDS 32 KB.
__global__ __launch_bounds__(512) void k_kv(const float* __restrict__ road_feat,
                                            const unsigned short* __restrict__ Wcb,
                                            const float* __restrict__ bcv,
                                            const float* __restrict__ extq,
                                            float* __restrict__ scores,
                                            unsigned short* __restrict__ V) {
    __shared__ unsigned short Xs[64 * 256];   // bf16, rows=pixels, cols=channels, swizzled
    char* Xc = (char*)Xs;
    int b  = blockIdx.x >> 6;
    int p0 = (blockIdx.x & 63) << 6;
    int t  = threadIdx.x;
    const float* rfb = road_feat + (size_t)b * 1048576;

    // stage: thread handles 2 adjacent channels x 4 pixels per iter -> packed u32 writes
    int c0 = 2 * (t >> 4);
    int j4 = (t & 15) * 4;
    #pragma unroll
    for (int it = 0; it < 4; ++it) {
        int c = c0 + 64 * it;
        f32x4 g0 = *(const f32x4*)(rfb + (size_t)c * 4096 + p0 + j4);
        f32x4 g1 = *(const f32x4*)(rfb + (size_t)(c + 1) * 4096 + p0 + j4);
        #pragma unroll
        for (int i = 0; i < 4; i++) {
            int j = j4 + i;
            unsigned int pk = (unsigned int)f2b(g0[i]) | ((unsigned int)f2b(g1[i]) << 16);
            *(unsigned int*)(Xc + ((j * 512 + 2 * c) ^ ((j & 15) << 4))) = pk;
        }
    }
    __syncthreads();

    int w = t >> 6, lane = t & 63, l15 = lane & 15, lhi = lane >> 4;
    int wm = w >> 2, wn = w & 3;

    f32x4 acc[2][8] = {};
    for (int kk = 0; kk < 8; kk++) {
        bf16x8 a[2];
        #pragma unroll
        for (int mi = 0; mi < 2; mi++) {
            int j = wm * 32 + mi * 16 + l15;
            int off = (j * 512 + (kk * 32 + 8 * lhi) * 2) ^ ((j & 15) << 4);
            a[mi] = *(const bf16x8*)((const char*)Xs + off);
        }
        #pragma unroll
        for (int ni = 0; ni < 8; ni++) {
            int n = wn * 128 + ni * 16 + l15;
            bf16x8 bf = *(const bf16x8*)(Wcb + (size_t)n * 256 + kk * 32 + 8 * lhi);
            acc[0][ni] = __builtin_amdgcn_mfma_f32_16x16x32_bf16(a[0], bf, acc[0][ni], 0, 0, 0);
            acc[1][ni] = __builtin_amdgcn_mfma_f32_16x16x32_bf16(a[1], bf, acc[1][ni], 0, 0, 0);
        }
    }

    if (wn < 2) {
        // K outputs (channels wn*128 .. +128): scores = (q . (k+bias)) * scale
        float qA[4], qB[4], bk[8];
        #pragma unroll
        for (int hl = 0; hl < 4; ++hl) {
            int hg = wn * 4 + hl;
            qA[hl] = extq[b * 256 + hg * 32 + l15];
            qB[hl] = extq[b * 256 + hg * 32 + 16 + l15];
        }
        #pragma unroll
        for (int ni = 0; ni < 8; ni++) bk[ni] = bcv[wn * 128 + ni * 16 + l15];
        #pragma unroll
        for (int mi = 0; mi < 2; mi++)
            #pragma unroll
            for (int r = 0; r < 4; r++) {
                int j = wm * 32 + mi * 16 + 4 * lhi + r;
                #pragma unroll
                for (int hl = 0; hl < 4; hl++) {
                    float s = (acc[mi][2 * hl][r] + bk[2 * hl]) * qA[hl]
                            + (acc[mi][2 * hl + 1][r] + bk[2 * hl + 1]) * qB[hl];
                    s += __shfl_xor(s, 1, 64);
                    s += __shfl_xor(s, 2, 64);
                    s += __shfl_xor(s, 4, 64);
                    s += __shfl_xor(s, 8, 64);
                    if (l15 == 0) {
                        int hg = wn * 4 + hl;
                        scores[(size_t)(b * 8 + hg) * 4096 + p0 + j] = s * 0.17677669529663687f;
                    }
                }
            }
    } else {
        // V outputs: bf16 store to V[b][n][p][d]
        #pragma unroll
        for (int ni = 0; ni < 8; ni++) {
            int n  = wn * 128 + ni * 16 + l15;      // 256..511
            int cv = n - 256;
            float bv = bcv[n];
            int nh = cv >> 5, d = cv & 31;
            unsigned short* vb = V + (size_t)(b * 8 + nh) * 131072 + d;
            #pragma unroll
            for (int mi = 0; mi < 2; mi++)
                #pragma unroll
                for (int r = 0; r < 4; r++) {
                    int j = wm * 32 + mi * 16 + 4 * lhi + r;
                    vb[(size_t)(p0 + j) * 32] = f2b(acc[mi][ni][r] + bv);
                }
        }
    }
}

// ---------------------------------------------------------------------------
// K3a: split-K attention pass 1. grid = 64 bn * 32 splits.
__global__ __launch_bounds__(256) void k_attn1(const float* __restrict__ scores,
                                               const unsigned short* __restrict__ V,
                                               float* __restrict__ pmax,
                                               float* __restrict__ psum,
                                               float* __restrict__ ppv) {
    int bn = blockIdx.x >> 5, sp = blockIdx.x & 31;
    int t = threadIdx.x;
    const float* sc = scores + (size_t)bn * 4096 + sp * 128;
    const unsigned short* vp = V + (size_t)bn * 131072 + (size_t)sp * 128 * 32;
    __shared__ float es[128];
    __shared__ float red[4];
    __shared__ float sm0;
    float s = (t < 128) ? sc[t] : -3e38f;
    float mx = s;
    for (int m = 32; m; m >>= 1) mx = fmaxf(mx, __shfl_xor(mx, m, 64));
    if ((t & 63) == 0) red[t >> 6] = mx;
    __syncthreads();
    if (t == 0) sm0 = fmaxf(fmaxf(red[0], red[1]), fmaxf(red[2], red[3]));
    __syncthreads();
    float gm = sm0;
    float e = (t < 128) ? expf(s - gm) : 0.f;
    if (t < 128) es[t] = e;
    float ssum = e;
    for (int m = 32; m; m >>= 1) ssum += __shfl_xor(ssum, m, 64);
    if ((t & 63) == 0) red[t >> 6] = ssum;
    __syncthreads();
    if (t == 0) {
        pmax[bn * 32 + sp] = gm;
        psum[bn * 32 + sp] = red[0] + red[1] + red[2] + red[3];
    }
    int d = t & 31, pg = t >> 5;
    float acc = 0.f;
    #pragma unroll 4
    for (int i = 0; i < 16; i++) {
        int p = pg + 8 * i;
        acc += es[p] * b2f(vp[(size_t)p * 32 + d]);
    }
    __shared__ float part[8][33];
    part[pg][d] = acc;
    __syncthreads();
    if (t < 32) {
        float a = 0.f;
        #pragma unroll
        for (int g = 0; g < 8; g++) a += part[g][t];
        ppv[(size_t)(bn * 32 + sp) * 32 + t] = a;
    }
}

// K3b: combine 32 splits per (b,n).
__global__ __launch_bounds__(64) void k_attn2(const float* __restrict__ pmax,
                                              const float* __restrict__ psum,
                                              const float* __restrict__ ppv,
                                              float* __restrict__ ext_head) {
    int bn = blockIdx.x, t = threadIdx.x;
    __shared__ float wgt[32];
    __shared__ float stot;
    float lm = (t < 32) ? pmax[bn * 32 + t] : -3e38f;
    float gm = lm;
    for (int m = 16; m; m >>= 1) gm = fmaxf(gm, __shfl_xor(gm, m, 64));
    if (t < 32) {
        float w = expf(lm - gm);
        wgt[t] = w;
        float ws_ = w * psum[bn * 32 + t];
        for (int m = 16; m; m >>= 1) ws_ += __shfl_xor(ws_, m, 64);
        if (t == 0) stot = ws_;
    }
    __syncthreads();
    float inv = 1.0f / stot;
    int d = t & 31, h = t >> 5;
    float a = 0.f;
    #pragma unroll
    for (int s2 = h * 16; s2 < h * 16 + 16; s2++)
        a += wgt[s2] * ppv[(size_t)(bn * 32 + s2) * 32 + d];
    a += __shfl_xor(a, 32, 64);
    if (t < 32) ext_head[bn * 32 + d] = a * inv;
}

// ---------------------------------------------------------------------------
// K4: ext_vec / ext_gate
__global__ __launch_bounds__(256) void k_vec(const float* __restrict__ ext_head,
                                             const float* __restrict__ ext_out_w,
                                             const float* __restrict__ ext_out_b,
                                             const float* __restrict__ mean_low,
                                             const float* __restrict__ gate_ext_w,
                                             const float* __restrict__ gate_ext_b,
                                             float* __restrict__ ext_vec,
                                             float* __restrict__ ext_gate) {
    int b = blockIdx.x, c = threadIdx.x;
    __shared__ float hd_[256], ev[256], ml[256];
    hd_[c] = ext_head[b * 256 + c];
    ml[c]  = mean_low[b * 256 + c];
    __syncthreads();
    float s = ext_out_b[c];
    #pragma unroll 4
    for (int k = 0; k < 256; k++) s += ext_out_w[c * 256 + k] * hd_[k];
    ext_vec[b * 256 + c] = s;
    ev[c] = s;
    __syncthreads();
    float z = gate_ext_b[c];
    #pragma unroll 4
    for (int k = 0; k < 256; k++)
        z += gate_ext_w[c * 512 + k] * ml[k] + gate_ext_w[c * 512 + 256 + k] * ev[k];
    ext_gate[b * 256 + c] = 1.0f / (1.0f + expf(-z));
}

// ---------------------------------------------------------------------------
// K5: ext_final
__global__ __launch_bounds__(256) void k_ext_final(const float* __restrict__ low,
                                                   const float* __restrict__ ext_vec,
                                                   const float* __restrict__ ext_gate,
                                                   float* __restrict__ out) {
    int idx = blockIdx.x * 256 + threadIdx.x;
    #pragma unroll
    for (int rep = 0; rep < 4; ++rep) {
        int i = idx + rep * 524288;
        int bc = i >> 10;
        float g = ext_gate[bc];
        float vv = ext_vec[bc];
        f32x4 L = *(const f32x4*)(low + (size_t)i * 4);
        f32x4 o;
        #pragma unroll
        for (int c = 0; c < 4; c++) o[c] = L[c] + g * (vv - L[c]);
        *(f32x4*)(out + (size_t)i * 4) = o;
    }
}

// ---------------------------------------------------------------------------
// K6: road gate GEMM + elementwise.
__global__ __launch_bounds__(512) void k_road(const float* __restrict__ high,
                                              const unsigned short* __restrict__ W3b,
                                              const float* __restrict__ rg_const,
                                              const float* __restrict__ road_vec,
                                              float* __restrict__ outbuf) {
    __shared__ float Xs[64 * 256];
    char* Xc = (char*)Xs;
    int b  = blockIdx.x >> 6;
    int p0 = (blockIdx.x & 63) << 6;
    int t  = threadIdx.x;
    const float* hb = high + (size_t)b * 1048576;

    for (int it = 0; it < 8; ++it) {
        int c  = (t >> 4) + it * 32;
        int j4 = (t & 15) * 4;
        f32x4 g = *(const f32x4*)(hb + (size_t)c * 4096 + p0 + j4);
        #pragma unroll
        for (int i = 0; i < 4; i++) {
            int j = j4 + i;
            *(float*)(Xc + ((j * 1024 + 4 * c) ^ ((j & 15) << 4))) = g[i];
        }
    }
    __syncthreads();

    int w = t >> 6, lane = t & 63, l15 = lane & 15, lhi = lane >> 4;
    int wm = w >> 2, wn = w & 3;
    f32x4 acc[2][4] = {};
    for (int kk = 0; kk < 8; kk++) {
        bf16x8 a[2];
        #pragma unroll
        for (int mi = 0; mi < 2; mi++) {
            int j = wm * 32 + mi * 16 + l15;
            int base = j * 1024 + (kk * 32 + 8 * lhi) * 4;
            int sw = (j & 15) << 4;
            f32x4 x0 = *(const f32x4*)(Xc + (base ^ sw));
            f32x4 x1 = *(const f32x4*)(Xc + ((base + 16) ^ sw));
            bf16x8 av;
            #pragma unroll
            for (int i = 0; i < 4; i++) {
                av[i]     = (short)f2b(x0[i]);
                av[4 + i] = (short)f2b(x1[i]);
            }
            a[mi] = av;
        }
        #pragma unroll
        for (int ni = 0; ni < 4; ni++) {
            int o = wn * 64 + ni * 16 + l15;
            bf16x8 bf = *(const bf16x8*)(W3b + (size_t)o * 256 + kk * 32 + 8 * lhi);
            acc[0][ni] = __builtin_amdgcn_mfma_f32_16x16x32_bf16(a[0], bf, acc[0][ni], 0, 0, 0);
            acc[1][ni] = __builtin_amdgcn_mfma_f32_16x16x32_bf16(a[1], bf, acc[1][ni], 0, 0, 0);
        }
    }
    __syncthreads();

    #pragma unroll
    for (int ni = 0; ni < 4; ni++) {
        int o = wn * 64 + ni * 16 + l15;
        float rc = rg_const[b * 256 + o];
        float rv = road_vec[b * 256 + o];
        #pragma unroll
        for (int mi = 0; mi < 2; mi++)
            #pragma unroll
            for (int r = 0; r < 4; r++) {
                int j = wm * 32 + mi * 16 + 4 * lhi + r;
                float* slot = (float*)(Xc + ((j * 1024 + 4 * o) ^ ((j & 15) << 4)));
                float z = acc[mi][ni][r] + rc;
                float gte = 1.0f / (1.0f + expf(-z));
                float hv = *slot;
                *slot = hv + gte * (rv - hv);
            }
    }
    __syncthreads();

    float* ob = outbuf + 8388608 + (size_t)b * 1048576;
    for (int it = 0; it < 8; ++it) {
        int c  = (t >> 4) + it * 32;
        int j4 = (t & 15) * 4;
        f32x4 o4;
        #pragma unroll
        for (int i = 0; i < 4; i++) {
            int j = j4 + i;
            o4[i] = *(const float*)(Xc + ((j * 1024 + 4 * c) ^ ((j & 15) << 4)));
        }
        *(f32x4*)(ob + (size_t)c * 4096 + p0 + j4) = o4;
    }
}

// ---------------------------------------------------------------------------
extern "C" void kernel_launch(void* const* d_in, const int* in_sizes, int n_in,
                              void* d_out, int out_size, void* d_ws, size_t ws_size,
                              hipStream_t stream) {
    const float* low         = (const float*)d_in[0];
    const float* high        = (const float*)d_in[1];
    const float* ext_context = (const float*)d_in[2];
    const float* road_feat   = (const float*)d_in[3];
    const float* ext_proj_w  = (const float*)d_in[4];
    const float* ext_proj_b  = (const float*)d_in[5];
    const float* road_proj_w = (const float*)d_in[6];
    const float* road_proj_b = (const float*)d_in[7];
    const float* ext_qkv_w   = (const float*)d_in[8];
    const float* ext_qkv_b   = (const float*)d_in[9];
    const float* road_qkv_w  = (const float*)d_in[10];
    const float* road_qkv_b  = (const float*)d_in[11];
    const float* ext_out_w   = (const float*)d_in[12];
    const float* ext_out_b   = (const float*)d_in[13];
    const float* road_out_w  = (const float*)d_in[14];
    const float* road_out_b  = (const float*)d_in[15];
    const float* gate_ext_w  = (const float*)d_in[16];
    const float* gate_ext_b  = (const float*)d_in[17];
    const float* gate_road_w = (const float*)d_in[18];
    const float* gate_road_b = (const float*)d_in[19];

    float* out = (float*)d_out;
    unsigned short* wsb = (unsigned short*)d_ws;
    unsigned short* Wcb = wsb;               // 131072 ushorts (256 KB)
    unsigned short* W3b = wsb + 131072;      // 65536 ushorts (128 KB)
    float* fw = (float*)((char*)d_ws + 524288);
    float* ext_q    = fw;
    float* road_vec = fw + 2048;
    float* rg_const = fw + 4096;
    float* ext_head = fw + 6144;
    float* ext_vec  = fw + 8192;
    float* ext_gate = fw + 10240;
    float* mean_low = fw + 12288;
    float* bcv      = fw + 14336;            // 512 floats
    float* scores = out;                             // ext half scratch
    unsigned short* V = (unsigned short*)(out + 8388608);  // road half scratch, bf16
    float* pmax = out + 2097152;
    float* psum = out + 2099200;
    float* ppv  = out + 2101248;

    k_prep<<<256, 256, 0, stream>>>(gate_road_w, W3b);
    k_wc<<<64, 256, 0, stream>>>(road_proj_w, road_qkv_w, road_proj_b, road_qkv_b, Wcb, bcv);
    k_tiny<<<8, 256, 0, stream>>>(ext_context, ext_proj_w, ext_proj_b, ext_qkv_w, ext_qkv_b,
                                  road_out_w, road_out_b, gate_road_w, gate_road_b,
                                  ext_q, road_vec, rg_const);
    k_mean<<<2048, 256, 0, stream>>>(low, mean_low);
    k_kv<<<512, 512, 0, stream>>>(road_feat, Wcb, bcv, ext_q, scores, V);
    k_attn1<<<2048, 256, 0, stream>>>(scores, V, pmax, psum, ppv);
    k_attn2<<<64, 64, 0, stream>>>(pmax, psum, ppv, ext_head);
    k_vec<<<8, 256, 0, stream>>>(ext_head, ext_out_w, ext_out_b, mean_low,
                                 gate_ext_w, gate_ext_b, ext_vec, ext_gate);
    k_ext_final<<<2048, 256, 0, stream>>>(low, ext_vec, ext_gate, out);
    k_road<<<512, 512, 0, stream>>>(high, W3b, rg_const, road_vec, out);
}

// Round 5
// 181.160 us; speedup vs baseline: 1.1298x; 1.1298x over previous
//
#include <hip/hip_runtime.h>

typedef short bf16x8 __attribute__((ext_vector_type(8)));
typedef float f32x4 __attribute__((ext_vector_type(4)));

__device__ __forceinline__ unsigned short f2b(float f) {
    unsigned int u = __builtin_bit_cast(unsigned int, f);
    unsigned int r = u + 0x7FFFu + ((u >> 16) & 1u);
    return (unsigned short)(r >> 16);
}

// ---------------------------------------------------------------------------
// K_setup: fused weight prep. grid 328 blocks x 256.
//   bid <256 : W3b = bf16(gate_road_w[:, :256])
//   256..319 : Wc fold (road_proj into road_qkv k/v rows) + bc
//   320..327 : tiny vector chains per batch b
__global__ __launch_bounds__(256) void k_setup(const float* __restrict__ w1,
                                               const float* __restrict__ wqkv,
                                               const float* __restrict__ b1,
                                               const float* __restrict__ bqkv,
                                               const float* __restrict__ gate_road_w,
                                               const float* __restrict__ gate_road_b,
                                               const float* __restrict__ ext_context,
                                               const float* __restrict__ ext_proj_w,
                                               const float* __restrict__ ext_proj_b,
                                               const float* __restrict__ ext_qkv_w,
                                               const float* __restrict__ ext_qkv_b,
                                               const float* __restrict__ road_out_w,
                                               const float* __restrict__ road_out_b,
                                               unsigned short* __restrict__ W3b,
                                               unsigned short* __restrict__ Wcb,
                                               float* __restrict__ bcv,
                                               float* __restrict__ ext_q,
                                               float* __restrict__ road_vec,
                                               float* __restrict__ rg_const) {
    int bid = blockIdx.x, t = threadIdx.x;
    __shared__ float sel[8][256];
    __shared__ float red[8][4];
    if (bid < 256) {
        int i = bid * 256 + t;
        int o = i >> 8, k = i & 255;
        W3b[i] = f2b(gate_road_w[o * 512 + k]);
    } else if (bid < 320) {
        int o0 = (bid - 256) * 8;
        #pragma unroll
        for (int r = 0; r < 8; r++) {
            int o = o0 + r;
            int c = (o < 256) ? o : o - 256;
            int g = (o < 256) ? 1 : 2;
            sel[r][t] = wqkv[(size_t)(3 * c + g) * 256 + t];
        }
        __syncthreads();
        float b1v = b1[t];
        #pragma unroll
        for (int r = 0; r < 8; r++) {
            float v = sel[r][t] * b1v;
            for (int m = 32; m; m >>= 1) v += __shfl_xor(v, m, 64);
            if ((t & 63) == 0) red[r][t >> 6] = v;
        }
        __syncthreads();
        if (t < 8) {
            int o = o0 + t;
            int c = (o < 256) ? o : o - 256;
            int g = (o < 256) ? 1 : 2;
            bcv[o] = red[t][0] + red[t][1] + red[t][2] + red[t][3] + bqkv[3 * c + g];
        }
        float acc[8] = {};
        #pragma unroll 4
        for (int m = 0; m < 256; m++) {
            float w1v = w1[(size_t)m * 256 + t];
            #pragma unroll
            for (int r = 0; r < 8; r++) acc[r] += sel[r][m] * w1v;
        }
        #pragma unroll
        for (int r = 0; r < 8; r++) Wcb[(size_t)(o0 + r) * 256 + t] = f2b(acc[r]);
    } else {
        int b = bid - 320, c = t;
        float* ctx  = sel[0];
        float* extp = sel[1];
        float* extv = sel[2];
        float* rv   = sel[3];
        if (c < 64) ctx[c] = ext_context[b * 64 + c];
        __syncthreads();
        float s = ext_proj_b[c];
        #pragma unroll 4
        for (int k = 0; k < 64; k++) s += ext_proj_w[c * 64 + k] * ctx[k];
        extp[c] = s;
        __syncthreads();
        float q = ext_qkv_b[c], v = ext_qkv_b[512 + c];
        #pragma unroll 4
        for (int k = 0; k < 256; k++) {
            float p = extp[k];
            q += ext_qkv_w[c * 256 + k] * p;
            v += ext_qkv_w[(512 + c) * 256 + k] * p;
        }
        ext_q[b * 256 + c] = q;
        extv[c] = v;
        __syncthreads();
        float r = road_out_b[c];
        #pragma unroll 4
        for (int k = 0; k < 256; k++) r += road_out_w[c * 256 + k] * extv[k];
        road_vec[b * 256 + c] = r;
        rv[c] = r;
        __syncthreads();
        float g = gate_road_b[c];
        #pragma unroll 4
        for (int k = 0; k < 256; k++) g += gate_road_w[c * 512 + 256 + k] * rv[k];
        rg_const[b * 256 + c] = g;
    }
}

// ---------------------------------------------------------------------------
// K_mean
__global__ __launch_bounds__(256) void k_mean(const float* __restrict__ low,
                                              float* __restrict__ mean_low) {
    int bc = blockIdx.x, t = threadIdx.x;
    const f32x4* p4 = (const f32x4*)(low + (size_t)bc * 4096);
    float s = 0.f;
    for (int i = t; i < 1024; i += 256) {
        f32x4 v = p4[i];
        s += v[0] + v[1] + v[2] + v[3];
    }
    for (int m = 32; m; m >>= 1) s += __shfl_xor(s, m, 64);
    __shared__ float red[4];
    if ((t & 63) == 0) red[t >> 6] = s;
    __syncthreads();
    if (t == 0) mean_low[bc] = (red[0] + red[1] + red[2] + red[3]) * (1.0f / 4096.0f);
}

// ---------------------------------------------------------------------------
// K2: fused KV-GEMM + tile-local attention partials.
// grid 512 (8 b x 64 px-tiles), block 512 (8 waves = 2 wm x 4 wn).
// Out per block: part[bid*264 + 0..8) = sum_j exp(s), [8..264) = sum_j exp(s)*v.
__global__ __launch_bounds__(512) void k_kv(const float* __restrict__ road_feat,
                                            const unsigned short* __restrict__ Wcb,
                                            const float* __restrict__ bcv,
                                            const float* __restrict__ extq,
                                            float* __restrict__ part) {
    __shared__ unsigned short Xs[64 * 256];   // bf16, rows=pixels, cols=channels, swizzled
    __shared__ float esh[8][64];              // exp(scores) per head x pixel
    __shared__ float pvp[2][256];             // per-wm partial PV
    char* Xc = (char*)Xs;
    int bid = blockIdx.x;
    int b  = bid >> 6;
    int p0 = (bid & 63) << 6;
    int t  = threadIdx.x;
    const float* rfb = road_feat + (size_t)b * 1048576;

    // stage: 2 adjacent channels x 4 pixels -> packed u32 LDS writes
    int c0 = 2 * (t >> 4);
    int j4 = (t & 15) * 4;
    #pragma unroll
    for (int it = 0; it < 4; ++it) {
        int c = c0 + 64 * it;
        f32x4 g0 = *(const f32x4*)(rfb + (size_t)c * 4096 + p0 + j4);
        f32x4 g1 = *(const f32x4*)(rfb + (size_t)(c + 1) * 4096 + p0 + j4);
        #pragma unroll
        for (int i = 0; i < 4; i++) {
            int j = j4 + i;
            unsigned int pk = (unsigned int)f2b(g0[i]) | ((unsigned int)f2b(g1[i]) << 16);
            *(unsigned int*)(Xc + ((j * 512 + 2 * c) ^ ((j & 15) << 4))) = pk;
        }
    }
    __syncthreads();

    int w = t >> 6, lane = t & 63, l15 = lane & 15, lhi = lane >> 4;
    int wm = w >> 2, wn = w & 3;

    f32x4 acc[2][8] = {};
    for (int kk = 0; kk < 8; kk++) {
        bf16x8 a[2];
        #pragma unroll
        for (int mi = 0; mi < 2; mi++) {
            int j = wm * 32 + mi * 16 + l15;
            int off = (j * 512 + (kk * 32 + 8 * lhi) * 2) ^ ((j & 15) << 4);
            a[mi] = *(const bf16x8*)((const char*)Xs + off);
        }
        #pragma unroll
        for (int ni = 0; ni < 8; ni++) {
            int n = wn * 128 + ni * 16 + l15;
            bf16x8 bf = *(const bf16x8*)(Wcb + (size_t)n * 256 + kk * 32 + 8 * lhi);
            acc[0][ni] = __builtin_amdgcn_mfma_f32_16x16x32_bf16(a[0], bf, acc[0][ni], 0, 0, 0);
            acc[1][ni] = __builtin_amdgcn_mfma_f32_16x16x32_bf16(a[1], bf, acc[1][ni], 0, 0, 0);
        }
    }

    if (wn < 2) {
        // K waves: s = q.(k+bk)*scale ; es = exp(s) -> LDS
        float qA[4], qB[4], bk[8];
        #pragma unroll
        for (int hl = 0; hl < 4; ++hl) {
            int hg = wn * 4 + hl;
            qA[hl] = extq[b * 256 + hg * 32 + l15];
            qB[hl] = extq[b * 256 + hg * 32 + 16 + l15];
        }
        #pragma unroll
        for (int ni = 0; ni < 8; ni++) bk[ni] = bcv[wn * 128 + ni * 16 + l15];
        #pragma unroll
        for (int mi = 0; mi < 2; mi++)
            #pragma unroll
            for (int r = 0; r < 4; r++) {
                int j = wm * 32 + mi * 16 + 4 * lhi + r;
                #pragma unroll
                for (int hl = 0; hl < 4; hl++) {
                    float s = (acc[mi][2 * hl][r] + bk[2 * hl]) * qA[hl]
                            + (acc[mi][2 * hl + 1][r] + bk[2 * hl + 1]) * qB[hl];
                    s += __shfl_xor(s, 1, 64);
                    s += __shfl_xor(s, 2, 64);
                    s += __shfl_xor(s, 4, 64);
                    s += __shfl_xor(s, 8, 64);
                    if (l15 == 0)
                        esh[wn * 4 + hl][j] = expf(s * 0.17677669529663687f);
                }
            }
    }
    __syncthreads();

    float* pb = part + (size_t)bid * 264;
    if (wn >= 2) {
        // V waves: partial PV = sum_j es[h][j]*(v+bv), reduce over lhi
        #pragma unroll
        for (int ni = 0; ni < 8; ni++) {
            int cv = (wn - 2) * 128 + ni * 16 + l15;
            int hg = (wn - 2) * 4 + (ni >> 1);
            float bv = bcv[256 + cv];
            float p = 0.f;
            #pragma unroll
            for (int mi = 0; mi < 2; mi++)
                #pragma unroll
                for (int r = 0; r < 4; r++) {
                    int j = wm * 32 + mi * 16 + 4 * lhi + r;
                    p += esh[hg][j] * (acc[mi][ni][r] + bv);
                }
            p += __shfl_xor(p, 16, 64);
            p += __shfl_xor(p, 32, 64);
            if (lhi == 0) pvp[wm][cv] = p;
        }
    } else {
        // K waves: per-head sum of es over the 64 pixels (2 heads per wave)
        int h0 = wn * 4 + wm * 2;
        float v0 = esh[h0][lane], v1 = esh[h0 + 1][lane];
        for (int m = 32; m; m >>= 1) {
            v0 += __shfl_xor(v0, m, 64);
            v1 += __shfl_xor(v1, m, 64);
        }
        if (lane == 0) { pb[h0] = v0; pb[h0 + 1] = v1; }
    }
    __syncthreads();
    if (t < 256) pb[8 + t] = pvp[0][t] + pvp[1][t];
}

// ---------------------------------------------------------------------------
// K4: combine attention partials -> ext_head, then ext_vec / ext_gate. 8 blocks.
__global__ __launch_bounds__(256) void k_vec(const float* __restrict__ part,
                                             const float* __restrict__ ext_out_w,
                                             const float* __restrict__ ext_out_b,
                                             const float* __restrict__ mean_low,
                                             const float* __restrict__ gate_ext_w,
                                             const float* __restrict__ gate_ext_b,
                                             float* __restrict__ ext_vec,
                                             float* __restrict__ ext_gate) {
    int b = blockIdx.x, c = threadIdx.x;
    __shared__ float hd_[256], ev[256], ml[256], tot[8];
    const float* pb = part + (size_t)b * 64 * 264;
    float a = 0.f;
    #pragma unroll 4
    for (int tile = 0; tile < 64; tile++) a += pb[tile * 264 + 8 + c];
    if (c < 8) {
        float s = 0.f;
        for (int tile = 0; tile < 64; tile++) s += pb[tile * 264 + c];
        tot[c] = 1.0f / s;
    }
    ml[c] = mean_low[b * 256 + c];
    __syncthreads();
    hd_[c] = a * tot[c >> 5];
    __syncthreads();
    float s = ext_out_b[c];
    #pragma unroll 4
    for (int k = 0; k < 256; k++) s += ext_out_w[c * 256 + k] * hd_[k];
    ext_vec[b * 256 + c] = s;
    ev[c] = s;
    __syncthreads();
    float z = gate_ext_b[c];
    #pragma unroll 4
    for (int k = 0; k < 256; k++)
        z += gate_ext_w[c * 512 + k] * ml[k] + gate_ext_w[c * 512 + 256 + k] * ev[k];
    ext_gate[b * 256 + c] = 1.0f / (1.0f + expf(-z));
}

// ---------------------------------------------------------------------------
// K5: ext_final
__global__ __launch_bounds__(256) void k_ext_final(const float* __restrict__ low,
                                                   const float* __restrict__ ext_vec,
                                                   const float* __restrict__ ext_gate,
                                                   float* __restrict__ out) {
    int idx = blockIdx.x * 256 + threadIdx.x;
    #pragma unroll
    for (int rep = 0; rep < 4; ++rep) {
        int i = idx + rep * 524288;
        int bc = i >> 10;
        float g = ext_gate[bc];
        float vv = ext_vec[bc];
        f32x4 L = *(const f32x4*)(low + (size_t)i * 4);
        f32x4 o;
        #pragma unroll
        for (int c = 0; c < 4; c++) o[c] = L[c] + g * (vv - L[c]);
        *(f32x4*)(out + (size_t)i * 4) = o;
    }
}

// ---------------------------------------------------------------------------
// K6: road gate GEMM + elementwise.
__global__ __launch_bounds__(512) void k_road(const float* __restrict__ high,
                                              const unsigned short* __restrict__ W3b,
                                              const float* __restrict__ rg_const,
                                              const float* __restrict__ road_vec,
                                              float* __restrict__ outbuf) {
    __shared__ float Xs[64 * 256];
    char* Xc = (char*)Xs;
    int b  = blockIdx.x >> 6;
    int p0 = (blockIdx.x & 63) << 6;
    int t  = threadIdx.x;
    const float* hb = high + (size_t)b * 1048576;

    for (int it = 0; it < 8; ++it) {
        int c  = (t >> 4) + it * 32;
        int j4 = (t & 15) * 4;
        f32x4 g = *(const f32x4*)(hb + (size_t)c * 4096 + p0 + j4);
        #pragma unroll
        for (int i = 0; i < 4; i++) {
            int j = j4 + i;
            *(float*)(Xc + ((j * 1024 + 4 * c) ^ ((j & 15) << 4))) = g[i];
        }
    }
    __syncthreads();

    int w = t >> 6, lane = t & 63, l15 = lane & 15, lhi = lane >> 4;
    int wm = w >> 2, wn = w & 3;
    f32x4 acc[2][4] = {};
    for (int kk = 0; kk < 8; kk++) {
        bf16x8 a[2];
        #pragma unroll
        for (int mi = 0; mi < 2; mi++) {
            int j = wm * 32 + mi * 16 + l15;
            int base = j * 1024 + (kk * 32 + 8 * lhi) * 4;
            int sw = (j & 15) << 4;
            f32x4 x0 = *(const f32x4*)(Xc + (base ^ sw));
            f32x4 x1 = *(const f32x4*)(Xc + ((base + 16) ^ sw));
            bf16x8 av;
            #pragma unroll
            for (int i = 0; i < 4; i++) {
                av[i]     = (short)f2b(x0[i]);
                av[4 + i] = (short)f2b(x1[i]);
            }
            a[mi] = av;
        }
        #pragma unroll
        for (int ni = 0; ni < 4; ni++) {
            int o = wn * 64 + ni * 16 + l15;
            bf16x8 bf = *(const bf16x8*)(W3b + (size_t)o * 256 + kk * 32 + 8 * lhi);
            acc[0][ni] = __builtin_amdgcn_mfma_f32_16x16x32_bf16(a[0], bf, acc[0][ni], 0, 0, 0);
            acc[1][ni] = __builtin_amdgcn_mfma_f32_16x16x32_bf16(a[1], bf, acc[1][ni], 0, 0, 0);
        }
    }
    __syncthreads();

    #pragma unroll
    for (int ni = 0; ni < 4; ni++) {
        int o = wn * 64 + ni * 16 + l15;
        float rc = rg_const[b * 256 + o];
        float rv = road_vec[b * 256 + o];
        #pragma unroll
        for (int mi = 0; mi < 2; mi++)
            #pragma unroll
            for (int r = 0; r < 4; r++) {
                int j = wm * 32 + mi * 16 + 4 * lhi + r;
                float* slot = (float*)(Xc + ((j * 1024 + 4 * o) ^ ((j & 15) << 4)));
                float z = acc[mi][ni][r] + rc;
                float gte = 1.0f / (1.0f + expf(-z));
                float hv = *slot;
                *slot = hv + gte * (rv - hv);
            }
    }
    __syncthreads();

    float* ob = outbuf + 8388608 + (size_t)b * 1048576;
    for (int it = 0; it < 8; ++it) {
        int c  = (t >> 4) + it * 32;
        int j4 = (t & 15) * 4;
        f32x4 o4;
        #pragma unroll
        for (int i = 0; i < 4; i++) {
            int j = j4 + i;
            o4[i] = *(const float*)(Xc + ((j * 1024 + 4 * c) ^ ((j & 15) << 4)));
        }
        *(f32x4*)(ob + (size_t)c * 4096 + p0 + j4) = o4;
    }
}

// ---------------------------------------------------------------------------
extern "C" void kernel_launch(void* const* d_in, const int* in_sizes, int n_in,
                              void* d_out, int out_size, void* d_ws, size_t ws_size,
                              hipStream_t stream) {
    const float* low         = (const float*)d_in[0];
    const float* high        = (const float*)d_in[1];
    const float* ext_context = (const float*)d_in[2];
    const float* road_feat   = (const float*)d_in[3];
    const float* ext_proj_w  = (const float*)d_in[4];
    const float* ext_proj_b  = (const float*)d_in[5];
    const float* road_proj_w = (const float*)d_in[6];
    const float* road_proj_b = (const float*)d_in[7];
    const float* ext_qkv_w   = (const float*)d_in[8];
    const float* ext_qkv_b   = (const float*)d_in[9];
    const float* road_qkv_w  = (const float*)d_in[10];
    const float* road_qkv_b  = (const float*)d_in[11];
    const float* ext_out_w   = (const float*)d_in[12];
    const float* ext_out_b   = (const float*)d_in[13];
    const float* road_out_w  = (const float*)d_in[14];
    const float* road_out_b  = (const float*)d_in[15];
    const float* gate_ext_w  = (const float*)d_in[16];
    const float* gate_ext_b  = (const float*)d_in[17];
    const float* gate_road_w = (const float*)d_in[18];
    const float* gate_road_b = (const float*)d_in[19];

    float* out = (float*)d_out;
    unsigned short* wsb = (unsigned short*)d_ws;
    unsigned short* Wcb = wsb;               // 131072 ushorts
    unsigned short* W3b = wsb + 131072;      // 65536 ushorts
    float* fw = (float*)((char*)d_ws + 524288);
    float* ext_q    = fw;
    float* road_vec = fw + 2048;
    float* rg_const = fw + 4096;
    float* ext_vec  = fw + 8192;
    float* ext_gate = fw + 10240;
    float* mean_low = fw + 12288;
    float* bcv      = fw + 14336;
    float* part = out + 2097152;   // 512*264 floats in ext-half dead zone (pre-K5)

    k_setup<<<328, 256, 0, stream>>>(road_proj_w, road_qkv_w, road_proj_b, road_qkv_b,
                                     gate_road_w, gate_road_b, ext_context,
                                     ext_proj_w, ext_proj_b, ext_qkv_w, ext_qkv_b,
                                     road_out_w, road_out_b,
                                     W3b, Wcb, bcv, ext_q, road_vec, rg_const);
    k_mean<<<2048, 256, 0, stream>>>(low, mean_low);
    k_kv<<<512, 512, 0, stream>>>(road_feat, Wcb, bcv, ext_q, part);
    k_vec<<<8, 256, 0, stream>>>(part, ext_out_w, ext_out_b, mean_low,
                                 gate_ext_w, gate_ext_b, ext_vec, ext_gate);
    k_ext_final<<<2048, 256, 0, stream>>>(low, ext_vec, ext_gate, out);
    k_road<<<512, 512, 0, stream>>>(high, W3b, rg_const, road_vec, out);
}

// Round 6
// 166.948 us; speedup vs baseline: 1.2260x; 1.0851x over previous
//
#include <hip/hip_runtime.h>

typedef short bf16x8 __attribute__((ext_vector_type(8)));
typedef float f32x4 __attribute__((ext_vector_type(4)));

__device__ __forceinline__ unsigned short f2b(float f) {
    unsigned int u = __builtin_bit_cast(unsigned int, f);
    unsigned int r = u + 0x7FFFu + ((u >> 16) & 1u);
    return (unsigned short)(r >> 16);
}

// ---------------------------------------------------------------------------
// K_setup: fused weight prep + mean(low). grid 2376 x 256.
//   bid <256   : W3b = bf16(gate_road_w[:, :256])
//   256..319   : Wc fold (road_proj into road_qkv k/v rows) + bc
//   320..327   : tiny vector chains per batch b
//   328..2375  : mean_low over spatial per (b,c)
__global__ __launch_bounds__(256) void k_setup(const float* __restrict__ w1,
                                               const float* __restrict__ wqkv,
                                               const float* __restrict__ b1,
                                               const float* __restrict__ bqkv,
                                               const float* __restrict__ gate_road_w,
                                               const float* __restrict__ gate_road_b,
                                               const float* __restrict__ ext_context,
                                               const float* __restrict__ ext_proj_w,
                                               const float* __restrict__ ext_proj_b,
                                               const float* __restrict__ ext_qkv_w,
                                               const float* __restrict__ ext_qkv_b,
                                               const float* __restrict__ road_out_w,
                                               const float* __restrict__ road_out_b,
                                               const float* __restrict__ low,
                                               unsigned short* __restrict__ W3b,
                                               unsigned short* __restrict__ Wcb,
                                               float* __restrict__ bcv,
                                               float* __restrict__ ext_q,
                                               float* __restrict__ road_vec,
                                               float* __restrict__ rg_const,
                                               float* __restrict__ mean_low) {
    int bid = blockIdx.x, t = threadIdx.x;
    __shared__ float sel[8][256];
    __shared__ float red[8][4];
    if (bid >= 328) {
        int bc = bid - 328;
        const f32x4* p4 = (const f32x4*)(low + (size_t)bc * 4096);
        float s = 0.f;
        for (int i = t; i < 1024; i += 256) {
            f32x4 v = p4[i];
            s += v[0] + v[1] + v[2] + v[3];
        }
        for (int m = 32; m; m >>= 1) s += __shfl_xor(s, m, 64);
        if ((t & 63) == 0) red[0][t >> 6] = s;
        __syncthreads();
        if (t == 0) mean_low[bc] = (red[0][0] + red[0][1] + red[0][2] + red[0][3]) * (1.0f / 4096.0f);
    } else if (bid < 256) {
        int i = bid * 256 + t;
        int o = i >> 8, k = i & 255;
        W3b[i] = f2b(gate_road_w[o * 512 + k]);
    } else if (bid < 320) {
        int o0 = (bid - 256) * 8;
        #pragma unroll
        for (int r = 0; r < 8; r++) {
            int o = o0 + r;
            int c = (o < 256) ? o : o - 256;
            int g = (o < 256) ? 1 : 2;
            sel[r][t] = wqkv[(size_t)(3 * c + g) * 256 + t];
        }
        __syncthreads();
        float b1v = b1[t];
        #pragma unroll
        for (int r = 0; r < 8; r++) {
            float v = sel[r][t] * b1v;
            for (int m = 32; m; m >>= 1) v += __shfl_xor(v, m, 64);
            if ((t & 63) == 0) red[r][t >> 6] = v;
        }
        __syncthreads();
        if (t < 8) {
            int o = o0 + t;
            int c = (o < 256) ? o : o - 256;
            int g = (o < 256) ? 1 : 2;
            bcv[o] = red[t][0] + red[t][1] + red[t][2] + red[t][3] + bqkv[3 * c + g];
        }
        float acc[8] = {};
        #pragma unroll 4
        for (int m = 0; m < 256; m++) {
            float w1v = w1[(size_t)m * 256 + t];
            #pragma unroll
            for (int r = 0; r < 8; r++) acc[r] += sel[r][m] * w1v;
        }
        #pragma unroll
        for (int r = 0; r < 8; r++) Wcb[(size_t)(o0 + r) * 256 + t] = f2b(acc[r]);
    } else {
        int b = bid - 320, c = t;
        float* ctx  = sel[0];
        float* extp = sel[1];
        float* extv = sel[2];
        float* rv   = sel[3];
        if (c < 64) ctx[c] = ext_context[b * 64 + c];
        __syncthreads();
        float s = ext_proj_b[c];
        #pragma unroll 4
        for (int k = 0; k < 64; k++) s += ext_proj_w[c * 64 + k] * ctx[k];
        extp[c] = s;
        __syncthreads();
        float q = ext_qkv_b[c], v = ext_qkv_b[512 + c];
        #pragma unroll 4
        for (int k = 0; k < 256; k++) {
            float p = extp[k];
            q += ext_qkv_w[c * 256 + k] * p;
            v += ext_qkv_w[(512 + c) * 256 + k] * p;
        }
        ext_q[b * 256 + c] = q;
        extv[c] = v;
        __syncthreads();
        float r = road_out_b[c];
        #pragma unroll 4
        for (int k = 0; k < 256; k++) r += road_out_w[c * 256 + k] * extv[k];
        road_vec[b * 256 + c] = r;
        rv[c] = r;
        __syncthreads();
        float g = gate_road_b[c];
        #pragma unroll 4
        for (int k = 0; k < 256; k++) g += gate_road_w[c * 512 + 256 + k] * rv[k];
        rg_const[b * 256 + c] = g;
    }
}

// ---------------------------------------------------------------------------
// K2: fused KV-GEMM + tile-local attention partials. 32-px tiles.
// grid 1024 (8 b x 128 tiles), block 512 (8 waves; w<4: K-channels, w>=4: V).
// Per block out: part[bid*264 + 0..8) = sum_j exp(s); [8..264) = sum_j exp(s)*v.
__global__ __launch_bounds__(512) void k_kv(const float* __restrict__ road_feat,
                                            const unsigned short* __restrict__ Wcb,
                                            const float* __restrict__ bcv,
                                            const float* __restrict__ extq,
                                            float* __restrict__ part) {
    __shared__ unsigned short Xs[32 * 256];   // bf16, rows=pixels(32), cols=channels, swizzled
    __shared__ float esh[8][32];              // exp(scores) head x pixel
    char* Xc = (char*)Xs;
    int bid = blockIdx.x;
    int b  = bid >> 7;
    int p0 = (bid & 127) << 5;
    int t  = threadIdx.x;
    const float* rfb = road_feat + (size_t)b * 1048576;

    // stage: 2 adjacent channels x 4 pixels -> packed u32 LDS writes
    int c0 = 2 * (t >> 3);
    int j4 = (t & 7) * 4;
    #pragma unroll
    for (int it = 0; it < 2; ++it) {
        int c = c0 + 128 * it;
        f32x4 g0 = *(const f32x4*)(rfb + (size_t)c * 4096 + p0 + j4);
        f32x4 g1 = *(const f32x4*)(rfb + (size_t)(c + 1) * 4096 + p0 + j4);
        #pragma unroll
        for (int i = 0; i < 4; i++) {
            int j = j4 + i;
            unsigned int pk = (unsigned int)f2b(g0[i]) | ((unsigned int)f2b(g1[i]) << 16);
            *(unsigned int*)(Xc + ((j * 512 + 2 * c) ^ ((j & 15) << 4))) = pk;
        }
    }
    __syncthreads();

    int w = t >> 6, lane = t & 63, l15 = lane & 15, lhi = lane >> 4;

    // wave w owns 64 output channels [w*64, w*64+64): 4 ni of 16.
    f32x4 acc[2][4] = {};
    for (int kk = 0; kk < 8; kk++) {
        bf16x8 a[2];
        #pragma unroll
        for (int mi = 0; mi < 2; mi++) {
            int j = mi * 16 + l15;
            int off = (j * 512 + (kk * 32 + 8 * lhi) * 2) ^ ((j & 15) << 4);
            a[mi] = *(const bf16x8*)((const char*)Xs + off);
        }
        #pragma unroll
        for (int ni = 0; ni < 4; ni++) {
            int n = w * 64 + ni * 16 + l15;
            bf16x8 bf = *(const bf16x8*)(Wcb + (size_t)n * 256 + kk * 32 + 8 * lhi);
            acc[0][ni] = __builtin_amdgcn_mfma_f32_16x16x32_bf16(a[0], bf, acc[0][ni], 0, 0, 0);
            acc[1][ni] = __builtin_amdgcn_mfma_f32_16x16x32_bf16(a[1], bf, acc[1][ni], 0, 0, 0);
        }
    }

    if (w < 4) {
        // K waves: heads 2w, 2w+1. s = q.(k+bk) * scale; es = exp -> LDS
        float qv[4], bk[4];
        #pragma unroll
        for (int ni = 0; ni < 4; ni++) {
            int n = w * 64 + ni * 16 + l15;
            qv[ni] = extq[b * 256 + n];
            bk[ni] = bcv[n];
        }
        #pragma unroll
        for (int mi = 0; mi < 2; mi++)
            #pragma unroll
            for (int r = 0; r < 4; r++) {
                int j = mi * 16 + 4 * lhi + r;
                #pragma unroll
                for (int hl = 0; hl < 2; hl++) {
                    float s = (acc[mi][2 * hl][r] + bk[2 * hl]) * qv[2 * hl]
                            + (acc[mi][2 * hl + 1][r] + bk[2 * hl + 1]) * qv[2 * hl + 1];
                    s += __shfl_xor(s, 1, 64);
                    s += __shfl_xor(s, 2, 64);
                    s += __shfl_xor(s, 4, 64);
                    s += __shfl_xor(s, 8, 64);
                    if (l15 == 0)
                        esh[w * 2 + hl][j] = expf(s * 0.17677669529663687f);
                }
            }
    }
    __syncthreads();

    float* pb = part + (size_t)bid * 264;
    if (w >= 4) {
        // V waves: partial PV over 32 px; reduce over lhi -> direct global store
        #pragma unroll
        for (int ni = 0; ni < 4; ni++) {
            int cv = (w - 4) * 64 + ni * 16 + l15;
            int hg = (w - 4) * 2 + (ni >> 1);
            float bv = bcv[256 + cv];
            float p = 0.f;
            #pragma unroll
            for (int mi = 0; mi < 2; mi++)
                #pragma unroll
                for (int r = 0; r < 4; r++) {
                    int j = mi * 16 + 4 * lhi + r;
                    p += esh[hg][j] * (acc[mi][ni][r] + bv);
                }
            p += __shfl_xor(p, 16, 64);
            p += __shfl_xor(p, 32, 64);
            if (lhi == 0) pb[8 + cv] = p;
        }
    } else {
        // K waves: per-head sum of es over 32 px (2 heads per wave)
        int h0 = w * 2;
        float v0 = (lane < 32) ? esh[h0][lane] : esh[h0 + 1][lane - 32];
        v0 += __shfl_xor(v0, 1, 64);
        v0 += __shfl_xor(v0, 2, 64);
        v0 += __shfl_xor(v0, 4, 64);
        v0 += __shfl_xor(v0, 8, 64);
        v0 += __shfl_xor(v0, 16, 64);
        if (lane == 0)  pb[h0] = v0;
        if (lane == 32) pb[h0 + 1] = v0;
    }
}

// ---------------------------------------------------------------------------
// K4: combine attention partials -> ext_head, then ext_vec / ext_gate. 8 blocks.
__global__ __launch_bounds__(256) void k_vec(const float* __restrict__ part,
                                             const float* __restrict__ ext_out_w,
                                             const float* __restrict__ ext_out_b,
                                             const float* __restrict__ mean_low,
                                             const float* __restrict__ gate_ext_w,
                                             const float* __restrict__ gate_ext_b,
                                             float* __restrict__ ext_vec,
                                             float* __restrict__ ext_gate) {
    int b = blockIdx.x, c = threadIdx.x;
    __shared__ float hd_[256], ev[256], ml[256], tot[8];
    const float* pb = part + (size_t)b * 128 * 264;
    float a = 0.f;
    #pragma unroll 4
    for (int tile = 0; tile < 128; tile++) a += pb[tile * 264 + 8 + c];
    if (c < 8) {
        float s = 0.f;
        for (int tile = 0; tile < 128; tile++) s += pb[tile * 264 + c];
        tot[c] = 1.0f / s;
    }
    ml[c] = mean_low[b * 256 + c];
    __syncthreads();
    hd_[c] = a * tot[c >> 5];
    __syncthreads();
    float s = ext_out_b[c];
    #pragma unroll 4
    for (int k = 0; k < 256; k++) s += ext_out_w[c * 256 + k] * hd_[k];
    ext_vec[b * 256 + c] = s;
    ev[c] = s;
    __syncthreads();
    float z = gate_ext_b[c];
    #pragma unroll 4
    for (int k = 0; k < 256; k++)
        z += gate_ext_w[c * 512 + k] * ml[k] + gate_ext_w[c * 512 + 256 + k] * ev[k];
    ext_gate[b * 256 + c] = 1.0f / (1.0f + expf(-z));
}

// ---------------------------------------------------------------------------
// K5: ext_final
__global__ __launch_bounds__(256) void k_ext_final(const float* __restrict__ low,
                                                   const float* __restrict__ ext_vec,
                                                   const float* __restrict__ ext_gate,
                                                   float* __restrict__ out) {
    int idx = blockIdx.x * 256 + threadIdx.x;
    #pragma unroll
    for (int rep = 0; rep < 4; ++rep) {
        int i = idx + rep * 524288;
        int bc = i >> 10;
        float g = ext_gate[bc];
        float vv = ext_vec[bc];
        f32x4 L = *(const f32x4*)(low + (size_t)i * 4);
        f32x4 o;
        #pragma unroll
        for (int c = 0; c < 4; c++) o[c] = L[c] + g * (vv - L[c]);
        *(f32x4*)(out + (size_t)i * 4) = o;
    }
}

// ---------------------------------------------------------------------------
// K6: road gate GEMM + elementwise. 32-px tiles, grid 1024.
// block 512 (8 waves), wave w owns 32 output channels (2 ni of 16), all 32 px.
__global__ __launch_bounds__(512) void k_road(const float* __restrict__ high,
                                              const unsigned short* __restrict__ W3b,
                                              const float* __restrict__ rg_const,
                                              const float* __restrict__ road_vec,
                                              float* __restrict__ outbuf) {
    __shared__ float Xs[32 * 256];   // f32, rows=pixels(32), swizzled
    char* Xc = (char*)Xs;
    int bid = blockIdx.x;
    int b  = bid >> 7;
    int p0 = (bid & 127) << 5;
    int t  = threadIdx.x;
    const float* hb = high + (size_t)b * 1048576;

    int c0 = t >> 3;
    int j4 = (t & 7) * 4;
    #pragma unroll
    for (int it = 0; it < 4; ++it) {
        int c = c0 + 64 * it;
        f32x4 g = *(const f32x4*)(hb + (size_t)c * 4096 + p0 + j4);
        #pragma unroll
        for (int i = 0; i < 4; i++) {
            int j = j4 + i;
            *(float*)(Xc + ((j * 1024 + 4 * c) ^ ((j & 15) << 4))) = g[i];
        }
    }
    __syncthreads();

    int w = t >> 6, lane = t & 63, l15 = lane & 15, lhi = lane >> 4;
    f32x4 acc[2][2] = {};
    for (int kk = 0; kk < 8; kk++) {
        bf16x8 a[2];
        #pragma unroll
        for (int mi = 0; mi < 2; mi++) {
            int j = mi * 16 + l15;
            int base = j * 1024 + (kk * 32 + 8 * lhi) * 4;
            int sw = (j & 15) << 4;
            f32x4 x0 = *(const f32x4*)(Xc + (base ^ sw));
            f32x4 x1 = *(const f32x4*)(Xc + ((base + 16) ^ sw));
            bf16x8 av;
            #pragma unroll
            for (int i = 0; i < 4; i++) {
                av[i]     = (short)f2b(x0[i]);
                av[4 + i] = (short)f2b(x1[i]);
            }
            a[mi] = av;
        }
        #pragma unroll
        for (int ni = 0; ni < 2; ni++) {
            int o = w * 32 + ni * 16 + l15;
            bf16x8 bf = *(const bf16x8*)(W3b + (size_t)o * 256 + kk * 32 + 8 * lhi);
            acc[0][ni] = __builtin_amdgcn_mfma_f32_16x16x32_bf16(a[0], bf, acc[0][ni], 0, 0, 0);
            acc[1][ni] = __builtin_amdgcn_mfma_f32_16x16x32_bf16(a[1], bf, acc[1][ni], 0, 0, 0);
        }
    }
    __syncthreads();

    #pragma unroll
    for (int ni = 0; ni < 2; ni++) {
        int o = w * 32 + ni * 16 + l15;
        float rc = rg_const[b * 256 + o];
        float rv = road_vec[b * 256 + o];
        #pragma unroll
        for (int mi = 0; mi < 2; mi++)
            #pragma unroll
            for (int r = 0; r < 4; r++) {
                int j = mi * 16 + 4 * lhi + r;
                float* slot = (float*)(Xc + ((j * 1024 + 4 * o) ^ ((j & 15) << 4)));
                float z = acc[mi][ni][r] + rc;
                float gte = 1.0f / (1.0f + expf(-z));
                float hv = *slot;
                *slot = hv + gte * (rv - hv);
            }
    }
    __syncthreads();

    float* ob = outbuf + 8388608 + (size_t)b * 1048576;
    #pragma unroll
    for (int it = 0; it < 4; ++it) {
        int c = c0 + 64 * it;
        f32x4 o4;
        #pragma unroll
        for (int i = 0; i < 4; i++) {
            int j = j4 + i;
            o4[i] = *(const float*)(Xc + ((j * 1024 + 4 * c) ^ ((j & 15) << 4)));
        }
        *(f32x4*)(ob + (size_t)c * 4096 + p0 + j4) = o4;
    }
}

// ---------------------------------------------------------------------------
extern "C" void kernel_launch(void* const* d_in, const int* in_sizes, int n_in,
                              void* d_out, int out_size, void* d_ws, size_t ws_size,
                              hipStream_t stream) {
    const float* low         = (const float*)d_in[0];
    const float* high        = (const float*)d_in[1];
    const float* ext_context = (const float*)d_in[2];
    const float* road_feat   = (const float*)d_in[3];
    const float* ext_proj_w  = (const float*)d_in[4];
    const float* ext_proj_b  = (const float*)d_in[5];
    const float* road_proj_w = (const float*)d_in[6];
    const float* road_proj_b = (const float*)d_in[7];
    const float* ext_qkv_w   = (const float*)d_in[8];
    const float* ext_qkv_b   = (const float*)d_in[9];
    const float* road_qkv_w  = (const float*)d_in[10];
    const float* road_qkv_b  = (const float*)d_in[11];
    const float* ext_out_w   = (const float*)d_in[12];
    const float* ext_out_b   = (const float*)d_in[13];
    const float* road_out_w  = (const float*)d_in[14];
    const float* road_out_b  = (const float*)d_in[15];
    const float* gate_ext_w  = (const float*)d_in[16];
    const float* gate_ext_b  = (const float*)d_in[17];
    const float* gate_road_w = (const float*)d_in[18];
    const float* gate_road_b = (const float*)d_in[19];

    float* out = (float*)d_out;
    unsigned short* wsb = (unsigned short*)d_ws;
    unsigned short* Wcb = wsb;               // 131072 ushorts
    unsigned short* W3b = wsb + 131072;      // 65536 ushorts
    float* fw = (float*)((char*)d_ws + 524288);
    float* ext_q    = fw;
    float* road_vec = fw + 2048;
    float* rg_const = fw + 4096;
    float* ext_vec  = fw + 8192;
    float* ext_gate = fw + 10240;
    float* mean_low = fw + 12288;
    float* bcv      = fw + 14336;
    float* part = out + 2097152;   // 1024*264 floats in ext-half dead zone (pre-K5)

    k_setup<<<2376, 256, 0, stream>>>(road_proj_w, road_qkv_w, road_proj_b, road_qkv_b,
                                      gate_road_w, gate_road_b, ext_context,
                                      ext_proj_w, ext_proj_b, ext_qkv_w, ext_qkv_b,
                                      road_out_w, road_out_b, low,
                                      W3b, Wcb, bcv, ext_q, road_vec, rg_const, mean_low);
    k_kv<<<1024, 512, 0, stream>>>(road_feat, Wcb, bcv, ext_q, part);
    k_vec<<<8, 256, 0, stream>>>(part, ext_out_w, ext_out_b, mean_low,
                                 gate_ext_w, gate_ext_b, ext_vec, ext_gate);
    k_ext_final<<<2048, 256, 0, stream>>>(low, ext_vec, ext_gate, out);
    k_road<<<1024, 512, 0, stream>>>(high, W3b, rg_const, road_vec, out);
}